// Round 11
// baseline (120.621 us; speedup 1.0000x reference)
//
#include <hip/hip_runtime.h>
#include <hip/hip_bf16.h>
#include <stdint.h>

#define N_Q 4096
#define N_K 4096
#define DIM 512

typedef float f32x4 __attribute__((ext_vector_type(4)));
typedef __bf16 bf16x8 __attribute__((ext_vector_type(8)));
typedef unsigned short u16x4 __attribute__((ext_vector_type(4)));
typedef int i32x4 __attribute__((ext_vector_type(4)));

__device__ __forceinline__ f32x4 mfma_bf16(bf16x8 a, bf16x8 b, f32x4 c) {
  return __builtin_amdgcn_mfma_f32_16x16x32_bf16(a, b, c, 0, 0, 0);
}

__device__ __forceinline__ i32x4 mfma_i8(i32x4 a, i32x4 b, i32x4 c) {
  return __builtin_amdgcn_mfma_i32_16x16x64_i8(a, b, c, 0, 0, 0);
}

__device__ __forceinline__ void gload16(const void* g, void* l) {
  __builtin_amdgcn_global_load_lds((const __attribute__((address_space(1))) void*)g,
                                   (__attribute__((address_space(3))) void*)l,
                                   16, 0, 0);
}

// x ~= hi + lo split (bf16), used by fallback qk_kernel only
__device__ __forceinline__ void split4(const f32x4 v, u16x4& h, u16x4& l) {
#pragma unroll
  for (int i = 0; i < 4; ++i) {
    float f = v[i];
    uint32_t u = __builtin_bit_cast(uint32_t, f);
    uint32_t hb = (u + 0x8000u) & 0xffff0000u;
    float hf = __builtin_bit_cast(float, hb);
    float lf = f - hf;
    h[i] = (unsigned short)(hb >> 16);
    l[i] = (unsigned short)(__builtin_bit_cast(uint32_t, lf) >> 16);
  }
}

__device__ __forceinline__ unsigned short bf16r(float f) {
  uint32_t u = __builtin_bit_cast(uint32_t, f);
  return (unsigned short)((u + 0x8000u) >> 16);
}

// ---------------------------------------------------------------------------
// Kernel 0 (fused prep): blocks [0,2048): i8 hi/lo quant of Q/K rows.
//                        blocks [2048,2560): Vt[d][k] = bf16(V[k][d]).
// ---------------------------------------------------------------------------
__global__ __launch_bounds__(256) void prep_kernel(const float* __restrict__ Q,
                                                   const float* __restrict__ K,
                                                   const float* __restrict__ V,
                                                   signed char* __restrict__ Xq8,
                                                   signed char* __restrict__ Xk8,
                                                   float* __restrict__ sclA,
                                                   float* __restrict__ sclB,
                                                   unsigned short* __restrict__ Vt) {
  __shared__ unsigned short t[64][72];
  const int bid = blockIdx.x;
  const int tid = threadIdx.x;

  if (bid < 2048) {
    const bool isK = bid >= 1024;
    const float* X = isK ? K : Q;
    signed char* X8 = isK ? Xk8 : Xq8;
    float* scl = isK ? sclB : sclA;
    const int lane = tid & 63;
    const int row = (isK ? bid - 1024 : bid) * 4 + (tid >> 6);

    f32x4 v[2];
    v[0] = *(const f32x4*)(X + (size_t)row * DIM + lane * 8);
    v[1] = *(const f32x4*)(X + (size_t)row * DIM + lane * 8 + 4);

    float mx = 0.f;
#pragma unroll
    for (int u = 0; u < 2; ++u)
#pragma unroll
      for (int j = 0; j < 4; ++j) mx = fmaxf(mx, fabsf(v[u][j]));
#pragma unroll
    for (int o = 32; o > 0; o >>= 1) mx = fmaxf(mx, __shfl_xor(mx, o, 64));

    const float s = fmaxf(mx, 1e-20f) * (1.0f / 127.0f);
    const float rinv = 1.0f / s;
    const float linv = 128.0f * rinv;

    uint32_t hw[2], lw[2];
#pragma unroll
    for (int u = 0; u < 2; ++u) {
      uint32_t hword = 0, lword = 0;
#pragma unroll
      for (int j = 0; j < 4; ++j) {
        float x = v[u][j];
        int h = __float2int_rn(x * rinv);
        float r = x - s * (float)h;
        int l = __float2int_rn(r * linv);
        hword |= ((uint32_t)(h & 0xff)) << (8 * j);
        lword |= ((uint32_t)(l & 0xff)) << (8 * j);
      }
      hw[u] = hword; lw[u] = lword;
    }
    uint2 hv; hv.x = hw[0]; hv.y = hw[1];
    uint2 lv; lv.x = lw[0]; lv.y = lw[1];
    *(uint2*)(X8 + (size_t)row * 1024 + lane * 8) = hv;
    *(uint2*)(X8 + (size_t)row * 1024 + 512 + lane * 8) = lv;
    if (lane == 0) scl[row] = s;
  } else {
    const int b2 = bid - 2048;
    const int d0 = (b2 & 7) * 64;
    const int k0 = (b2 >> 3) * 64;
#pragma unroll
    for (int c = 0; c < 4; ++c) {
      int kr = (tid >> 4) + c * 16;
      f32x4 v = *(const f32x4*)(V + (size_t)(k0 + kr) * DIM + d0 + (tid & 15) * 4);
#pragma unroll
      for (int j = 0; j < 4; ++j) t[(tid & 15) * 4 + j][kr] = bf16r(v[j]);
    }
    __syncthreads();
#pragma unroll
    for (int c = 0; c < 2; ++c) {
      int d = (tid >> 3) + c * 32;
      int k = (tid & 7) * 8;
      *(uint4*)(Vt + (size_t)(d0 + d) * N_K + k0 + k) = *(const uint4*)&t[d][k];
    }
  }
}

// ---------------------------------------------------------------------------
// Kernel 1 (v6): i8 hi/lo QK^T, phase-split schedule.
// 128x128 tile, 512 thr (8 waves, 2x4; wave tile 64x32), 3 LDS bufs (96 KB),
// ONE barrier per K-step. Per iter: entry vmcnt(4)+s_barrier; B-frags read
// once to regs; 4 phases = {1 A-frag ds_read pair, 1 stage-unit gload into
// buf (t+2)%3, 6 MFMA, sched_barrier(0)}. Loads span phases (counted vmcnt,
// never 0 mid-loop); stage target buffer is never read this iter or next,
// so no second barrier. Buffer t+3 reuse is fenced by the t+1 entry barrier.
// ---------------------------------------------------------------------------
__global__ __launch_bounds__(512, 2) void qk6_kernel(const signed char* __restrict__ Xq8,
                                                     const signed char* __restrict__ Xk8,
                                                     const float* __restrict__ sclA,
                                                     const float* __restrict__ sclB,
                                                     float* __restrict__ S) {
  __shared__ __align__(16) char smem[98304];   // 3 bufs x (A 16K | B 16K)

  const int tid = threadIdx.x;
  const int lane = tid & 63, wid = tid >> 6;   // 8 waves
  const int wr = wid >> 2, wc = wid & 3;       // 2x4 grid; wave tile 64x32

  const int bid = blockIdx.x;                  // 1024 blocks, %8==0 bijective
  const int b = (bid & 7) * 128 + (bid >> 3);
  const int rbase = (b >> 5) * 128;
  const int cbase = (b & 31) * 128;

  const i32x4 izero = {0, 0, 0, 0};
  i32x4 acc_hh[4][2], acc_x[4][2];
#pragma unroll
  for (int m = 0; m < 4; ++m)
#pragma unroll
    for (int n = 0; n < 2; ++n) { acc_hh[m][n] = izero; acc_x[m][n] = izero; }

  // stage unit u (0..3): u&1 selects row-half j, u<2 => A (Xq8) else B (Xk8).
  // 512 thr x 1 gload16 covers 64 rows x 128B per unit. LDS dest linear:
  // buf + (A?0:16384) + j*8192 + wid*1024 (+ lane*16 by HW).
  auto stage_unit = [&](int buf, int t, int u) {
    const int j = u & 1;
    const int r = j * 64 + (tid >> 3);
    const int sc = (tid & 7) ^ (r & 7);
    const int colb = (sc < 4) ? (t * 64 + sc * 16) : (512 + t * 64 + (sc & 3) * 16);
    const signed char* g = ((u < 2) ? Xq8 + (size_t)(rbase + r) * 1024
                                    : Xk8 + (size_t)(cbase + r) * 1024) + colb;
    uint32_t off = (uint32_t)(buf * 32768 + ((u < 2) ? 0 : 16384) + j * 8192 + wid * 1024);
    off = (uint32_t)__builtin_amdgcn_readfirstlane((int)off);
    gload16(g, smem + off);
  };

  // prologue: tiles 0,1 into bufs 0,1 (8 loads/thread outstanding)
#pragma unroll
  for (int u = 0; u < 4; ++u) stage_unit(0, 0, u);
#pragma unroll
  for (int u = 0; u < 4; ++u) stage_unit(1, 1, u);

  const int kc = lane >> 4;
  for (int t = 0; t < 8; ++t) {
    if (t < 7) asm volatile("s_waitcnt vmcnt(4)" ::: "memory");
    else       asm volatile("s_waitcnt vmcnt(0)" ::: "memory");
    __builtin_amdgcn_s_barrier();
    const int cur = t % 3;
    const int nxt = (t + 2) % 3;
    const bool st = (t + 2 < 8);
    const char* bA = smem + cur * 32768;
    const char* bB = bA + 16384;

    // B-frags once per iter, held in regs across phases
    i32x4 bh[2], bl[2];
#pragma unroll
    for (int n = 0; n < 2; ++n) {
      int row = wc * 32 + n * 16 + (lane & 15);
      bh[n] = *(const i32x4*)(bB + row * 128 + ((kc ^ (row & 7)) << 4));
      bl[n] = *(const i32x4*)(bB + row * 128 + (((4 + kc) ^ (row & 7)) << 4));
    }

#pragma unroll
    for (int m = 0; m < 4; ++m) {
      if (st) stage_unit(nxt, t + 2, m);
      int row = wr * 64 + m * 16 + (lane & 15);
      i32x4 ah = *(const i32x4*)(bA + row * 128 + ((kc ^ (row & 7)) << 4));
      i32x4 al = *(const i32x4*)(bA + row * 128 + (((4 + kc) ^ (row & 7)) << 4));
      __builtin_amdgcn_s_setprio(1);
#pragma unroll
      for (int n = 0; n < 2; ++n) {
        acc_hh[m][n] = mfma_i8(ah, bh[n], acc_hh[m][n]);
        acc_x[m][n]  = mfma_i8(ah, bl[n], acc_x[m][n]);
        acc_x[m][n]  = mfma_i8(al, bh[n], acc_x[m][n]);
      }
      __builtin_amdgcn_s_setprio(0);
      __builtin_amdgcn_sched_barrier(0);
    }
  }

#pragma unroll
  for (int m = 0; m < 4; ++m) {
    int row0 = rbase + wr * 64 + m * 16 + (lane >> 4) * 4;
    float sa[4];
#pragma unroll
    for (int j = 0; j < 4; ++j) sa[j] = sclA[row0 + j];
#pragma unroll
    for (int n = 0; n < 2; ++n) {
      int col = cbase + wc * 32 + n * 16 + (lane & 15);
      float sb = sclB[col];
#pragma unroll
      for (int j = 0; j < 4; ++j) {
        float f = (float)acc_hh[m][n][j] + (float)acc_x[m][n][j] * 0.0078125f;
        S[(size_t)(row0 + j) * N_K + col] = sa[j] * sb * f;
      }
    }
  }
}

// ---------------------------------------------------------------------------
// Kernel 1-fallback: S = Q*K^T with in-loop bf16 split (no ws)
// ---------------------------------------------------------------------------
__global__ __launch_bounds__(256, 2) void qk_kernel(const float* __restrict__ Q,
                                                    const float* __restrict__ K,
                                                    float* __restrict__ S) {
  __shared__ __align__(16) char sAh[16384];
  __shared__ __align__(16) char sAl[16384];
  __shared__ __align__(16) char sBh[16384];
  __shared__ __align__(16) char sBl[16384];

  const int tid = threadIdx.x;
  const int rbase = blockIdx.y * 128;
  const int cbase = blockIdx.x * 128;
  const int lane = tid & 63, wid = tid >> 6;
  const int wr = wid >> 1, wc = wid & 1;
  const int lr = lane & 15, lk = (lane >> 4) * 8;

  const int srow = tid >> 4;
  const int scol = (tid & 15) * 4;

  f32x4 qr[8], kr[8];
#pragma unroll
  for (int p = 0; p < 8; ++p) {
    int r = p * 16 + srow;
    qr[p] = *(const f32x4*)(Q + (size_t)(rbase + r) * DIM + scol);
    kr[p] = *(const f32x4*)(K + (size_t)(cbase + r) * DIM + scol);
  }

  const f32x4 fzero = {0.f, 0.f, 0.f, 0.f};
  f32x4 acc[4][4];
#pragma unroll
  for (int m = 0; m < 4; ++m)
#pragma unroll
    for (int n = 0; n < 4; ++n) acc[m][n] = fzero;

  for (int kk = 0; kk < DIM / 64; ++kk) {
    __syncthreads();
#pragma unroll
    for (int p = 0; p < 8; ++p) {
      int r = p * 16 + srow;
      uint32_t bo = (uint32_t)(r * 128) + (uint32_t)((scol * 2) ^ ((r & 7) << 4));
      u16x4 qh, ql, kh, kl;
      split4(qr[p], qh, ql);
      split4(kr[p], kh, kl);
      *(u16x4*)(sAh + bo) = qh;
      *(u16x4*)(sAl + bo) = ql;
      *(u16x4*)(sBh + bo) = kh;
      *(u16x4*)(sBl + bo) = kl;
    }
    __syncthreads();
    if (kk < DIM / 64 - 1) {
#pragma unroll
      for (int p = 0; p < 8; ++p) {
        int r = p * 16 + srow;
        qr[p] = *(const f32x4*)(Q + (size_t)(rbase + r) * DIM + (kk + 1) * 64 + scol);
        kr[p] = *(const f32x4*)(K + (size_t)(cbase + r) * DIM + (kk + 1) * 64 + scol);
      }
    }
#pragma unroll
    for (int kh = 0; kh < 2; ++kh) {
      bf16x8 a_h[4], a_l[4], b_h[4], b_l[4];
#pragma unroll
      for (int m = 0; m < 4; ++m) {
        int row = wr * 64 + m * 16 + lr;
        uint32_t co = (uint32_t)(((kh * 32 + lk) * 2) ^ ((row & 7) << 4));
        a_h[m] = *(const bf16x8*)(sAh + row * 128 + co);
        a_l[m] = *(const bf16x8*)(sAl + row * 128 + co);
      }
#pragma unroll
      for (int n = 0; n < 4; ++n) {
        int row = wc * 64 + n * 16 + lr;
        uint32_t co = (uint32_t)(((kh * 32 + lk) * 2) ^ ((row & 7) << 4));
        b_h[n] = *(const bf16x8*)(sBh + row * 128 + co);
        b_l[n] = *(const bf16x8*)(sBl + row * 128 + co);
      }
#pragma unroll
      for (int m = 0; m < 4; ++m)
#pragma unroll
        for (int n = 0; n < 4; ++n) {
          acc[m][n] = mfma_bf16(a_h[m], b_h[n], acc[m][n]);
          acc[m][n] = mfma_bf16(a_h[m], b_l[n], acc[m][n]);
          acc[m][n] = mfma_bf16(a_l[m], b_h[n], acc[m][n]);
        }
    }
  }

#pragma unroll
  for (int m = 0; m < 4; ++m) {
    int row = rbase + wr * 64 + m * 16 + (lane >> 4) * 4;
#pragma unroll
    for (int n = 0; n < 4; ++n) {
      int col = cbase + wc * 64 + n * 16 + lr;
#pragma unroll
      for (int j = 0; j < 4; ++j)
        S[(size_t)(row + j) * N_K + col] = acc[m][n][j];
    }
  }
}

// ---------------------------------------------------------------------------
// Kernel 2: row softmax in place + bf16 copy to ws
// ---------------------------------------------------------------------------
__global__ __launch_bounds__(256) void softmax_kernel(float* __restrict__ P,
                                                      unsigned short* __restrict__ Pb) {
  const int tid = threadIdx.x;
  const int wid = tid >> 6, lane = tid & 63;
  float* p = P + (size_t)blockIdx.x * N_K;

  f32x4 v[4];
  float mx = -3.0e38f;
#pragma unroll
  for (int i = 0; i < 4; ++i) {
    v[i] = *(const f32x4*)(p + i * 1024 + tid * 4);
    mx = fmaxf(mx, fmaxf(fmaxf(v[i][0], v[i][1]), fmaxf(v[i][2], v[i][3])));
  }
#pragma unroll
  for (int o = 32; o > 0; o >>= 1) mx = fmaxf(mx, __shfl_xor(mx, o, 64));
  __shared__ float redM[4];
  __shared__ float redS[4];
  if (lane == 0) redM[wid] = mx;
  __syncthreads();
  mx = fmaxf(fmaxf(redM[0], redM[1]), fmaxf(redM[2], redM[3]));

  float s = 0.f;
#pragma unroll
  for (int i = 0; i < 4; ++i) {
#pragma unroll
    for (int j = 0; j < 4; ++j) {
      v[i][j] = __expf(v[i][j] - mx);
      s += v[i][j];
    }
  }
#pragma unroll
  for (int o = 32; o > 0; o >>= 1) s += __shfl_xor(s, o, 64);
  if (lane == 0) redS[wid] = s;
  __syncthreads();
  s = redS[0] + redS[1] + redS[2] + redS[3];
  const float inv = 1.0f / s;

  unsigned short* pb = Pb + (size_t)blockIdx.x * N_K;
#pragma unroll
  for (int i = 0; i < 4; ++i) {
    v[i] *= inv;
    *(f32x4*)(p + i * 1024 + tid * 4) = v[i];
    u16x4 h;
#pragma unroll
    for (int j = 0; j < 4; ++j) h[j] = bf16r(v[i][j]);
    *(u16x4*)(pb + i * 1024 + tid * 4) = h;
  }
}

// ---------------------------------------------------------------------------
// Kernel 3 (v5): Opart[z] = Pb[:, z-range] * Vt[:, z-range]^T — R7 verbatim.
// ---------------------------------------------------------------------------
__global__ __launch_bounds__(256, 2) void pv5_kernel(const unsigned short* __restrict__ Pb,
                                                     const unsigned short* __restrict__ Vt,
                                                     float* __restrict__ Opart) {
  __shared__ __align__(16) char smem[65536];

  const int tid = threadIdx.x;
  const int lane = tid & 63, wid = tid >> 6;
  const int wr = wid >> 1, wc = wid & 1;
  const int rbase = blockIdx.y * 128;
  const int cbase = blockIdx.x * 128;
  const int k0 = blockIdx.z * 1024;
  float* Out = Opart + (size_t)blockIdx.z * ((size_t)N_Q * DIM);

  const int lrow = lane >> 3;
  const int lchk = lane & 7;

  const f32x4 fzero = {0.f, 0.f, 0.f, 0.f};
  f32x4 acc[4][4];
#pragma unroll
  for (int m = 0; m < 4; ++m)
#pragma unroll
    for (int n = 0; n < 4; ++n) acc[m][n] = fzero;

  auto stage = [&](int buf, int t) {
    const size_t kel = (size_t)k0 + ((size_t)t << 6);
#pragma unroll
    for (int i = 0; i < 4; ++i) {
      const int rr = (wid << 5) + (i << 3) + lrow;
      const int gc = lchk ^ (rr & 7);
      const void* gA = (const void*)(Pb + (size_t)(rbase + rr) * N_K + kel + (gc << 3));
      uint32_t off = (uint32_t)(buf * 32768 + (((wid << 5) + (i << 3)) << 7));
      off = (uint32_t)__builtin_amdgcn_readfirstlane((int)off);
      gload16(gA, smem + off);
    }
#pragma unroll
    for (int i = 0; i < 4; ++i) {
      const int rr = (wid << 5) + (i << 3) + lrow;
      const int gc = lchk ^ (rr & 7);
      const void* gB = (const void*)(Vt + (size_t)(cbase + rr) * N_K + kel + (gc << 3));
      uint32_t off = (uint32_t)(buf * 32768 + 16384 + (((wid << 5) + (i << 3)) << 7));
      off = (uint32_t)__builtin_amdgcn_readfirstlane((int)off);
      gload16(gB, smem + off);
    }
  };

  auto compute = [&](int buf) {
    const char* bA = smem + buf * 32768;
    const char* bB = bA + 16384;
#pragma unroll
    for (int kh = 0; kh < 2; ++kh) {
      bf16x8 a[4], bfr[4];
#pragma unroll
      for (int m = 0; m < 4; ++m) {
        int row = (wr << 6) + (m << 4) + (lane & 15);
        uint32_t co = (uint32_t)(((((kh << 2) + (lane >> 4)) << 4)) ^ ((row & 7) << 4));
        a[m] = *(const bf16x8*)(bA + row * 128 + co);
      }
#pragma unroll
      for (int n = 0; n < 4; ++n) {
        int row = (wc << 6) + (n << 4) + (lane & 15);
        uint32_t co = (uint32_t)(((((kh << 2) + (lane >> 4)) << 4)) ^ ((row & 7) << 4));
        bfr[n] = *(const bf16x8*)(bB + row * 128 + co);
      }
      __builtin_amdgcn_s_setprio(1);
#pragma unroll
      for (int m = 0; m < 4; ++m)
#pragma unroll
        for (int n = 0; n < 4; ++n)
          acc[m][n] = mfma_bf16(a[m], bfr[n], acc[m][n]);
      __builtin_amdgcn_s_setprio(0);
    }
  };

  stage(0, 0);
  stage(1, 1);
  for (int t = 0; t < 16; ++t) {
    if (t < 15) asm volatile("s_waitcnt vmcnt(8)" ::: "memory");
    else        asm volatile("s_waitcnt vmcnt(0)" ::: "memory");
    __builtin_amdgcn_s_barrier();
    compute(t & 1);
    asm volatile("s_waitcnt lgkmcnt(0)" ::: "memory");
    __builtin_amdgcn_sched_barrier(0);
    __builtin_amdgcn_s_barrier();
    if (t + 2 < 16) stage(t & 1, t + 2);
  }

#pragma unroll
  for (int m = 0; m < 4; ++m) {
    int row = rbase + wr * 64 + m * 16 + (lane >> 4) * 4;
#pragma unroll
    for (int n = 0; n < 4; ++n) {
      int col = cbase + wc * 64 + n * 16 + (lane & 15);
#pragma unroll
      for (int j = 0; j < 4; ++j)
        Out[(size_t)(row + j) * DIM + col] = acc[m][n][j];
    }
  }
}

__global__ __launch_bounds__(256) void reduce_kernel(float* __restrict__ O,
                                                     const float* __restrict__ Opart) {
  size_t i = ((size_t)blockIdx.x * 256 + threadIdx.x) * 4;
  f32x4 s = *(const f32x4*)(Opart + i);
#pragma unroll
  for (int z = 1; z < 4; ++z)
    s += *(const f32x4*)(Opart + (size_t)z * ((size_t)N_Q * DIM) + i);
  *(f32x4*)(O + i) = s;
}

// ---------------------------------------------------------------------------
// Fallback softmax/PV (no/small ws): R1-proven path.
// ---------------------------------------------------------------------------
__global__ __launch_bounds__(256) void softmax_fb_kernel(float* __restrict__ P) {
  const int tid = threadIdx.x;
  const int wid = tid >> 6, lane = tid & 63;
  float* p = P + (size_t)blockIdx.x * N_K;

  f32x4 v[4];
  float mx = -3.0e38f;
#pragma unroll
  for (int i = 0; i < 4; ++i) {
    v[i] = *(const f32x4*)(p + i * 1024 + tid * 4);
    mx = fmaxf(mx, fmaxf(fmaxf(v[i][0], v[i][1]), fmaxf(v[i][2], v[i][3])));
  }
#pragma unroll
  for (int o = 32; o > 0; o >>= 1) mx = fmaxf(mx, __shfl_xor(mx, o, 64));
  __shared__ float redM[4];
  __shared__ float redS[4];
  if (lane == 0) redM[wid] = mx;
  __syncthreads();
  mx = fmaxf(fmaxf(redM[0], redM[1]), fmaxf(redM[2], redM[3]));

  float s = 0.f;
#pragma unroll
  for (int i = 0; i < 4; ++i)
#pragma unroll
    for (int j = 0; j < 4; ++j) {
      v[i][j] = __expf(v[i][j] - mx);
      s += v[i][j];
    }
#pragma unroll
  for (int o = 32; o > 0; o >>= 1) s += __shfl_xor(s, o, 64);
  if (lane == 0) redS[wid] = s;
  __syncthreads();
  s = redS[0] + redS[1] + redS[2] + redS[3];
  const float inv = 1.0f / s;
#pragma unroll
  for (int i = 0; i < 4; ++i) {
    v[i] *= inv;
    *(f32x4*)(p + i * 1024 + tid * 4) = v[i];
  }
}

__global__ __launch_bounds__(512, 2) void pv_kernel(const float* __restrict__ P,
                                                    const float* __restrict__ V,
                                                    float* __restrict__ O) {
  __shared__ __align__(16) char sA[16384];
  __shared__ __align__(16) char sB[16384];

  const int tid = threadIdx.x;
  const int rbase = blockIdx.y * 128;
  const int cbase = blockIdx.x * 128;
  const int lane = tid & 63, wid = tid >> 6;
  const int wr = wid >> 2, wc = wid & 3;
  const int lr = lane & 15, lk = (lane >> 4) * 8;

  const int a_row = tid >> 4;
  const int a_col = (tid & 15) * 4;
  const int b_c = tid & 127;
  const int b_oct = tid >> 7;

  f32x4 areg[4];
  float breg[4][4];
#pragma unroll
  for (int p = 0; p < 4; ++p) {
    int r = p * 32 + a_row;
    areg[p] = *(const f32x4*)(P + (size_t)(rbase + r) * N_K + a_col);
  }
#pragma unroll
  for (int g = 0; g < 4; ++g) {
    int kr0 = b_oct * 4 + g * 16;
#pragma unroll
    for (int i = 0; i < 4; ++i)
      breg[g][i] = V[(size_t)(kr0 + i) * DIM + cbase + b_c];
  }

  const f32x4 fzero = {0.f, 0.f, 0.f, 0.f};
  f32x4 acc[4][2];
#pragma unroll
  for (int m = 0; m < 4; ++m)
#pragma unroll
    for (int n = 0; n < 2; ++n) acc[m][n] = fzero;

  for (int kk = 0; kk < N_K / 64; ++kk) {
    __syncthreads();
#pragma unroll
    for (int p = 0; p < 4; ++p) {
      int r = p * 32 + a_row;
      uint32_t bo = (uint32_t)(r * 128) + (uint32_t)((a_col * 2) ^ ((r & 7) << 4));
      u16x4 hv;
#pragma unroll
      for (int i = 0; i < 4; ++i) hv[i] = bf16r(areg[p][i]);
      *(u16x4*)(sA + bo) = hv;
    }
#pragma unroll
    for (int g = 0; g < 4; ++g) {
      int kr0 = b_oct * 4 + g * 16;
      uint32_t bo = (uint32_t)(b_c * 128) + (uint32_t)((kr0 * 2) ^ ((b_c & 7) << 4));
      u16x4 hv;
#pragma unroll
      for (int i = 0; i < 4; ++i) hv[i] = bf16r(breg[g][i]);
      *(u16x4*)(sB + bo) = hv;
    }
    __syncthreads();
    if (kk < N_K / 64 - 1) {
#pragma unroll
      for (int p = 0; p < 4; ++p) {
        int r = p * 32 + a_row;
        areg[p] = *(const f32x4*)(P + (size_t)(rbase + r) * N_K + (kk + 1) * 64 + a_col);
      }
#pragma unroll
      for (int g = 0; g < 4; ++g) {
        int kr0 = b_oct * 4 + g * 16;
#pragma unroll
        for (int i = 0; i < 4; ++i)
          breg[g][i] = V[(size_t)((kk + 1) * 64 + kr0 + i) * DIM + cbase + b_c];
      }
    }
#pragma unroll
    for (int kh = 0; kh < 2; ++kh) {
      bf16x8 af[4], bf[2];
#pragma unroll
      for (int m = 0; m < 4; ++m) {
        int row = wr * 64 + m * 16 + lr;
        uint32_t co = (uint32_t)(((kh * 32 + lk) * 2) ^ ((row & 7) << 4));
        af[m] = *(const bf16x8*)(sA + row * 128 + co);
      }
#pragma unroll
      for (int n = 0; n < 2; ++n) {
        int row = wc * 32 + n * 16 + lr;
        uint32_t co = (uint32_t)(((kh * 32 + lk) * 2) ^ ((row & 7) << 4));
        bf[n] = *(const bf16x8*)(sB + row * 128 + co);
      }
#pragma unroll
      for (int m = 0; m < 4; ++m)
#pragma unroll
        for (int n = 0; n < 2; ++n)
          acc[m][n] = mfma_bf16(af[m], bf[n], acc[m][n]);
    }
  }

#pragma unroll
  for (int m = 0; m < 4; ++m) {
    int row = rbase + wr * 64 + m * 16 + (lane >> 4) * 4;
#pragma unroll
    for (int n = 0; n < 2; ++n) {
      int col = cbase + wc * 32 + n * 16 + lr;
#pragma unroll
      for (int j = 0; j < 4; ++j)
        O[(size_t)(row + j) * DIM + col] = acc[m][n][j];
    }
  }
}

extern "C" void kernel_launch(void* const* d_in, const int* in_sizes, int n_in,
                              void* d_out, int out_size, void* d_ws, size_t ws_size,
                              hipStream_t stream) {
  const float* Q = (const float*)d_in[0];
  const float* K = (const float*)d_in[1];
  const float* V = (const float*)d_in[2];
  float* O = (float*)d_out;                       // [4096, 512]
  float* P = O + (size_t)N_Q * DIM;               // [4096, 4096] probs

  const size_t PB_BYTES = (size_t)N_Q * N_K * 2;          // 32 MB
  const size_t VT_BYTES = (size_t)DIM * N_K * 2;          // 4 MB
  const size_t SCL_BYTES = 65536;                          // 64 KB
  const size_t OP_BYTES = (size_t)N_Q * DIM * 4;          // 8 MB per split

  if (ws_size >= PB_BYTES + VT_BYTES + SCL_BYTES + 4 * OP_BYTES) {
    char* wsb = (char*)d_ws;
    // Xq8/Xk8 (4 MB each) alias the first 8 MB of Pb — dead before softmax.
    signed char* Xq8 = (signed char*)wsb;
    signed char* Xk8 = Xq8 + (size_t)N_Q * 1024;
    unsigned short* Pb = (unsigned short*)wsb;
    unsigned short* Vt = (unsigned short*)(wsb + PB_BYTES);
    float* sclA = (float*)(wsb + PB_BYTES + VT_BYTES);
    float* sclB = sclA + N_Q;
    float* Opart = (float*)(wsb + PB_BYTES + VT_BYTES + SCL_BYTES);

    prep_kernel<<<2560, 256, 0, stream>>>(Q, K, V, Xq8, Xk8, sclA, sclB, Vt);
    qk6_kernel<<<1024, 512, 0, stream>>>(Xq8, Xk8, sclA, sclB, P);
    softmax_kernel<<<N_Q, 256, 0, stream>>>(P, Pb);
    pv5_kernel<<<dim3(DIM / 128, N_Q / 128, 4), 256, 0, stream>>>(Pb, Vt, Opart);
    reduce_kernel<<<(N_Q * DIM) / (256 * 4), 256, 0, stream>>>(O, Opart);
  } else {
    qk_kernel<<<dim3(N_K / 128, N_Q / 128), 256, 0, stream>>>(Q, K, P);
    softmax_fb_kernel<<<N_Q, 256, 0, stream>>>(P);
    pv_kernel<<<dim3(DIM / 128, N_Q / 128), 512, 0, stream>>>(P, V, O);
  }
}

// Round 12
// 110.756 us; speedup vs baseline: 1.0891x; 1.0891x over previous
//
#include <hip/hip_runtime.h>
#include <hip/hip_bf16.h>
#include <stdint.h>

#define N_Q 4096
#define N_K 4096
#define DIM 512

typedef float f32x4 __attribute__((ext_vector_type(4)));
typedef __bf16 bf16x8 __attribute__((ext_vector_type(8)));
typedef unsigned short u16x4 __attribute__((ext_vector_type(4)));
typedef int i32x4 __attribute__((ext_vector_type(4)));

__device__ __forceinline__ f32x4 mfma_bf16(bf16x8 a, bf16x8 b, f32x4 c) {
  return __builtin_amdgcn_mfma_f32_16x16x32_bf16(a, b, c, 0, 0, 0);
}

__device__ __forceinline__ i32x4 mfma_i8(i32x4 a, i32x4 b, i32x4 c) {
  return __builtin_amdgcn_mfma_i32_16x16x64_i8(a, b, c, 0, 0, 0);
}

__device__ __forceinline__ void gload16(const void* g, void* l) {
  __builtin_amdgcn_global_load_lds((const __attribute__((address_space(1))) void*)g,
                                   (__attribute__((address_space(3))) void*)l,
                                   16, 0, 0);
}

// x ~= hi + lo split (bf16), used by fallback qk_kernel only
__device__ __forceinline__ void split4(const f32x4 v, u16x4& h, u16x4& l) {
#pragma unroll
  for (int i = 0; i < 4; ++i) {
    float f = v[i];
    uint32_t u = __builtin_bit_cast(uint32_t, f);
    uint32_t hb = (u + 0x8000u) & 0xffff0000u;
    float hf = __builtin_bit_cast(float, hb);
    float lf = f - hf;
    h[i] = (unsigned short)(hb >> 16);
    l[i] = (unsigned short)(__builtin_bit_cast(uint32_t, lf) >> 16);
  }
}

__device__ __forceinline__ unsigned short bf16r(float f) {
  uint32_t u = __builtin_bit_cast(uint32_t, f);
  return (unsigned short)((u + 0x8000u) >> 16);
}

// ---------------------------------------------------------------------------
// Kernel 0: per-row i8 two-level quantization of Q (y=0) and K (y=1).
// X[r][k] ~= s_r*(h + l/128), h in [-127,127], l in [-64,64], |err| <= s_r/256.
// Layout: X8[r] = [hi 512 bytes | lo 512 bytes]; scl[r] = s_r.
// One wave per row (block = 4 rows).
// ---------------------------------------------------------------------------
__global__ __launch_bounds__(256) void quant_kernel(const float* __restrict__ Q,
                                                    const float* __restrict__ K,
                                                    signed char* __restrict__ Xq8,
                                                    signed char* __restrict__ Xk8,
                                                    float* __restrict__ sclA,
                                                    float* __restrict__ sclB) {
  const float* X = blockIdx.y ? K : Q;
  signed char* X8 = blockIdx.y ? Xk8 : Xq8;
  float* scl = blockIdx.y ? sclB : sclA;

  const int lane = threadIdx.x & 63;
  const int row = blockIdx.x * 4 + (threadIdx.x >> 6);

  f32x4 v[2];
  v[0] = *(const f32x4*)(X + (size_t)row * DIM + lane * 8);
  v[1] = *(const f32x4*)(X + (size_t)row * DIM + lane * 8 + 4);

  float mx = 0.f;
#pragma unroll
  for (int u = 0; u < 2; ++u)
#pragma unroll
    for (int j = 0; j < 4; ++j) mx = fmaxf(mx, fabsf(v[u][j]));
#pragma unroll
  for (int o = 32; o > 0; o >>= 1) mx = fmaxf(mx, __shfl_xor(mx, o, 64));

  const float s = fmaxf(mx, 1e-20f) * (1.0f / 127.0f);
  const float rinv = 1.0f / s;
  const float linv = 128.0f * rinv;

  uint32_t hw[2], lw[2];
#pragma unroll
  for (int u = 0; u < 2; ++u) {
    uint32_t hword = 0, lword = 0;
#pragma unroll
    for (int j = 0; j < 4; ++j) {
      float x = v[u][j];
      int h = __float2int_rn(x * rinv);
      float r = x - s * (float)h;
      int l = __float2int_rn(r * linv);
      hword |= ((uint32_t)(h & 0xff)) << (8 * j);
      lword |= ((uint32_t)(l & 0xff)) << (8 * j);
    }
    hw[u] = hword; lw[u] = lword;
  }
  uint2 hv; hv.x = hw[0]; hv.y = hw[1];
  uint2 lv; lv.x = lw[0]; lv.y = lw[1];
  *(uint2*)(X8 + (size_t)row * 1024 + lane * 8) = hv;
  *(uint2*)(X8 + (size_t)row * 1024 + 512 + lane * 8) = lv;
  if (lane == 0) scl[row] = s;
}

// ---------------------------------------------------------------------------
// Kernel 1 (v3): S = Q*K^T via per-row i8 hi/lo, 3 i8-MFMAs (hh, hl, lh).
// BM=BN=128, BK=64 orig-k, 256 thr (4 waves 2x2, wave 64x64 = 4x4 frags).
// LDS tile per operand: [128 rows][hi 64B | lo 64B] = 128B rows, chunk-XOR
// swizzled via pre-swizzled global source (rule #21), dbuf + gload16 (T3-min).
// S = sA[r]*sB[c]*(HH + X/128). XCD swizzle on the 1024-block grid.
// ---------------------------------------------------------------------------
__global__ __launch_bounds__(256, 2) void qk3_kernel(const signed char* __restrict__ Xq8,
                                                     const signed char* __restrict__ Xk8,
                                                     const float* __restrict__ sclA,
                                                     const float* __restrict__ sclB,
                                                     float* __restrict__ S) {
  __shared__ __align__(16) char smem[65536];   // 2 bufs x (A 16K + B 16K)

  const int tid = threadIdx.x;
  const int lane = tid & 63, wid = tid >> 6;
  const int wr = wid >> 1, wc = wid & 1;

  const int bid = blockIdx.x;
  const int b = (bid & 7) * 128 + (bid >> 3);
  const int rbase = (b >> 5) * 128;
  const int cbase = (b & 31) * 128;

  const int lrow = lane >> 3;   // 0..7
  const int lchk = lane & 7;    // 0..7 (16B chunk)

  const i32x4 izero = {0, 0, 0, 0};
  i32x4 acc_hh[4][4], acc_x[4][4];
#pragma unroll
  for (int m = 0; m < 4; ++m)
#pragma unroll
    for (int n = 0; n < 4; ++n) { acc_hh[m][n] = izero; acc_x[m][n] = izero; }

  auto stage = [&](int buf, int t) {
#pragma unroll
    for (int i = 0; i < 4; ++i) {
      const int r = (wid << 5) + (i << 3) + lrow;
      const int sc = lchk ^ (r & 7);
      const int colb = (sc < 4) ? (t * 64 + sc * 16) : (512 + t * 64 + (sc & 3) * 16);
      const signed char* g = Xq8 + (size_t)(rbase + r) * 1024 + colb;
      uint32_t off = (uint32_t)(buf * 32768 + (((wid << 5) + (i << 3)) << 7));
      off = (uint32_t)__builtin_amdgcn_readfirstlane((int)off);
      gload16(g, smem + off);
    }
#pragma unroll
    for (int i = 0; i < 4; ++i) {
      const int r = (wid << 5) + (i << 3) + lrow;
      const int sc = lchk ^ (r & 7);
      const int colb = (sc < 4) ? (t * 64 + sc * 16) : (512 + t * 64 + (sc & 3) * 16);
      const signed char* g = Xk8 + (size_t)(cbase + r) * 1024 + colb;
      uint32_t off = (uint32_t)(buf * 32768 + 16384 + (((wid << 5) + (i << 3)) << 7));
      off = (uint32_t)__builtin_amdgcn_readfirstlane((int)off);
      gload16(g, smem + off);
    }
  };

  auto compute = [&](int buf) {
    const char* bA = smem + buf * 32768;
    const char* bB = bA + 16384;
    const int kc = lane >> 4;   // 0..3, 16 k each
    i32x4 ah[4], al[4], bh[4], bl[4];
#pragma unroll
    for (int m = 0; m < 4; ++m) {
      int row = (wr << 6) + (m << 4) + (lane & 15);
      ah[m] = *(const i32x4*)(bA + row * 128 + ((kc ^ (row & 7)) << 4));
      al[m] = *(const i32x4*)(bA + row * 128 + (((4 + kc) ^ (row & 7)) << 4));
    }
#pragma unroll
    for (int n = 0; n < 4; ++n) {
      int row = (wc << 6) + (n << 4) + (lane & 15);
      bh[n] = *(const i32x4*)(bB + row * 128 + ((kc ^ (row & 7)) << 4));
      bl[n] = *(const i32x4*)(bB + row * 128 + (((4 + kc) ^ (row & 7)) << 4));
    }
#pragma unroll
    for (int m = 0; m < 4; ++m)
#pragma unroll
      for (int n = 0; n < 4; ++n) {
        acc_hh[m][n] = mfma_i8(ah[m], bh[n], acc_hh[m][n]);
        acc_x[m][n]  = mfma_i8(ah[m], bl[n], acc_x[m][n]);
        acc_x[m][n]  = mfma_i8(al[m], bh[n], acc_x[m][n]);
      }
  };

  stage(0, 0);
  __syncthreads();
  int cur = 0;
  for (int t = 0; t < 8; ++t) {
    if (t + 1 < 8) stage(cur ^ 1, t + 1);
    compute(cur);
    __syncthreads();
    cur ^= 1;
  }

#pragma unroll
  for (int m = 0; m < 4; ++m) {
    int row0 = rbase + wr * 64 + m * 16 + (lane >> 4) * 4;
    float sa[4];
#pragma unroll
    for (int j = 0; j < 4; ++j) sa[j] = sclA[row0 + j];
#pragma unroll
    for (int n = 0; n < 4; ++n) {
      int col = cbase + wc * 64 + n * 16 + (lane & 15);
      float sb = sclB[col];
#pragma unroll
      for (int j = 0; j < 4; ++j) {
        float f = (float)acc_hh[m][n][j] + (float)acc_x[m][n][j] * 0.0078125f;
        S[(size_t)(row0 + j) * N_K + col] = sa[j] * sb * f;
      }
    }
  }
}

// ---------------------------------------------------------------------------
// Kernel 1-fallback: S = Q*K^T with in-loop bf16 split (no ws)
// ---------------------------------------------------------------------------
__global__ __launch_bounds__(256, 2) void qk_kernel(const float* __restrict__ Q,
                                                    const float* __restrict__ K,
                                                    float* __restrict__ S) {
  __shared__ __align__(16) char sAh[16384];
  __shared__ __align__(16) char sAl[16384];
  __shared__ __align__(16) char sBh[16384];
  __shared__ __align__(16) char sBl[16384];

  const int tid = threadIdx.x;
  const int rbase = blockIdx.y * 128;
  const int cbase = blockIdx.x * 128;
  const int lane = tid & 63, wid = tid >> 6;
  const int wr = wid >> 1, wc = wid & 1;
  const int lr = lane & 15, lk = (lane >> 4) * 8;

  const int srow = tid >> 4;
  const int scol = (tid & 15) * 4;

  f32x4 qr[8], kr[8];
#pragma unroll
  for (int p = 0; p < 8; ++p) {
    int r = p * 16 + srow;
    qr[p] = *(const f32x4*)(Q + (size_t)(rbase + r) * DIM + scol);
    kr[p] = *(const f32x4*)(K + (size_t)(cbase + r) * DIM + scol);
  }

  const f32x4 fzero = {0.f, 0.f, 0.f, 0.f};
  f32x4 acc[4][4];
#pragma unroll
  for (int m = 0; m < 4; ++m)
#pragma unroll
    for (int n = 0; n < 4; ++n) acc[m][n] = fzero;

  for (int kk = 0; kk < DIM / 64; ++kk) {
    __syncthreads();
#pragma unroll
    for (int p = 0; p < 8; ++p) {
      int r = p * 16 + srow;
      uint32_t bo = (uint32_t)(r * 128) + (uint32_t)((scol * 2) ^ ((r & 7) << 4));
      u16x4 qh, ql, kh, kl;
      split4(qr[p], qh, ql);
      split4(kr[p], kh, kl);
      *(u16x4*)(sAh + bo) = qh;
      *(u16x4*)(sAl + bo) = ql;
      *(u16x4*)(sBh + bo) = kh;
      *(u16x4*)(sBl + bo) = kl;
    }
    __syncthreads();
    if (kk < DIM / 64 - 1) {
#pragma unroll
      for (int p = 0; p < 8; ++p) {
        int r = p * 16 + srow;
        qr[p] = *(const f32x4*)(Q + (size_t)(rbase + r) * DIM + (kk + 1) * 64 + scol);
        kr[p] = *(const f32x4*)(K + (size_t)(cbase + r) * DIM + (kk + 1) * 64 + scol);
      }
    }
#pragma unroll
    for (int kh = 0; kh < 2; ++kh) {
      bf16x8 a_h[4], a_l[4], b_h[4], b_l[4];
#pragma unroll
      for (int m = 0; m < 4; ++m) {
        int row = wr * 64 + m * 16 + lr;
        uint32_t co = (uint32_t)(((kh * 32 + lk) * 2) ^ ((row & 7) << 4));
        a_h[m] = *(const bf16x8*)(sAh + row * 128 + co);
        a_l[m] = *(const bf16x8*)(sAl + row * 128 + co);
      }
#pragma unroll
      for (int n = 0; n < 4; ++n) {
        int row = wc * 64 + n * 16 + lr;
        uint32_t co = (uint32_t)(((kh * 32 + lk) * 2) ^ ((row & 7) << 4));
        b_h[n] = *(const bf16x8*)(sBh + row * 128 + co);
        b_l[n] = *(const bf16x8*)(sBl + row * 128 + co);
      }
#pragma unroll
      for (int m = 0; m < 4; ++m)
#pragma unroll
        for (int n = 0; n < 4; ++n) {
          acc[m][n] = mfma_bf16(a_h[m], b_h[n], acc[m][n]);
          acc[m][n] = mfma_bf16(a_h[m], b_l[n], acc[m][n]);
          acc[m][n] = mfma_bf16(a_l[m], b_h[n], acc[m][n]);
        }
    }
  }

#pragma unroll
  for (int m = 0; m < 4; ++m) {
    int row = rbase + wr * 64 + m * 16 + (lane >> 4) * 4;
#pragma unroll
    for (int n = 0; n < 4; ++n) {
      int col = cbase + wc * 64 + n * 16 + lr;
#pragma unroll
      for (int j = 0; j < 4; ++j)
        S[(size_t)(row + j) * N_K + col] = acc[m][n][j];
    }
  }
}

// ---------------------------------------------------------------------------
// Kernel 2: row softmax in place + bf16 copy to ws
// ---------------------------------------------------------------------------
__global__ __launch_bounds__(256) void softmax_kernel(float* __restrict__ P,
                                                      unsigned short* __restrict__ Pb) {
  const int tid = threadIdx.x;
  const int wid = tid >> 6, lane = tid & 63;
  float* p = P + (size_t)blockIdx.x * N_K;

  f32x4 v[4];
  float mx = -3.0e38f;
#pragma unroll
  for (int i = 0; i < 4; ++i) {
    v[i] = *(const f32x4*)(p + i * 1024 + tid * 4);
    mx = fmaxf(mx, fmaxf(fmaxf(v[i][0], v[i][1]), fmaxf(v[i][2], v[i][3])));
  }
#pragma unroll
  for (int o = 32; o > 0; o >>= 1) mx = fmaxf(mx, __shfl_xor(mx, o, 64));
  __shared__ float redM[4];
  __shared__ float redS[4];
  if (lane == 0) redM[wid] = mx;
  __syncthreads();
  mx = fmaxf(fmaxf(redM[0], redM[1]), fmaxf(redM[2], redM[3]));

  float s = 0.f;
#pragma unroll
  for (int i = 0; i < 4; ++i) {
#pragma unroll
    for (int j = 0; j < 4; ++j) {
      v[i][j] = __expf(v[i][j] - mx);
      s += v[i][j];
    }
  }
#pragma unroll
  for (int o = 32; o > 0; o >>= 1) s += __shfl_xor(s, o, 64);
  if (lane == 0) redS[wid] = s;
  __syncthreads();
  s = redS[0] + redS[1] + redS[2] + redS[3];
  const float inv = 1.0f / s;

  unsigned short* pb = Pb ? (Pb + (size_t)blockIdx.x * N_K) : nullptr;
#pragma unroll
  for (int i = 0; i < 4; ++i) {
    v[i] *= inv;
    *(f32x4*)(p + i * 1024 + tid * 4) = v[i];
    if (pb) {
      u16x4 h;
#pragma unroll
      for (int j = 0; j < 4; ++j) h[j] = bf16r(v[i][j]);
      *(u16x4*)(pb + i * 1024 + tid * 4) = h;
    }
  }
}

// ---------------------------------------------------------------------------
// Kernel 2b: Vt[d][k] = bf16(V[k][d])
// ---------------------------------------------------------------------------
__global__ __launch_bounds__(256) void vt_kernel(const float* __restrict__ V,
                                                 unsigned short* __restrict__ Vt) {
  __shared__ unsigned short t[64][72];
  const int tid = threadIdx.x;
  const int d0 = blockIdx.x * 64;
  const int k0 = blockIdx.y * 64;

#pragma unroll
  for (int c = 0; c < 4; ++c) {
    int kr = (tid >> 4) + c * 16;
    f32x4 v = *(const f32x4*)(V + (size_t)(k0 + kr) * DIM + d0 + (tid & 15) * 4);
#pragma unroll
    for (int j = 0; j < 4; ++j) t[(tid & 15) * 4 + j][kr] = bf16r(v[j]);
  }
  __syncthreads();
#pragma unroll
  for (int c = 0; c < 2; ++c) {
    int d = (tid >> 3) + c * 32;
    int k = (tid & 7) * 8;
    *(uint4*)(Vt + (size_t)(d0 + d) * N_K + k0 + k) = *(const uint4*)&t[d][k];
  }
}

// ---------------------------------------------------------------------------
// Kernel 3 (v3): Opart[z] = Pb[:, z-range] * Vt[:, z-range]^T
// ---------------------------------------------------------------------------
__global__ __launch_bounds__(256, 2) void pv3_kernel(const unsigned short* __restrict__ Pb,
                                                     const unsigned short* __restrict__ Vt,
                                                     float* __restrict__ Opart,
                                                     int kspan) {
  __shared__ __align__(16) char smem[65536];

  const int tid = threadIdx.x;
  const int lane = tid & 63, wid = tid >> 6;
  const int wr = wid >> 1, wc = wid & 1;
  const int rbase = blockIdx.y * 128;
  const int cbase = blockIdx.x * 128;
  const int k0 = blockIdx.z * kspan;
  float* Out = Opart + (size_t)blockIdx.z * ((size_t)N_Q * DIM);

  const int lrow = lane >> 3;
  const int lchk = lane & 7;
  const int iters = kspan >> 6;

  const f32x4 fzero = {0.f, 0.f, 0.f, 0.f};
  f32x4 acc[4][4];
#pragma unroll
  for (int m = 0; m < 4; ++m)
#pragma unroll
    for (int n = 0; n < 4; ++n) acc[m][n] = fzero;

  auto stage = [&](int buf, int t) {
    const size_t kel = (size_t)k0 + ((size_t)t << 6);
#pragma unroll
    for (int i = 0; i < 4; ++i) {
      const int rr = (wid << 5) + (i << 3) + lrow;
      const int gc = lchk ^ (rr & 7);
      const void* gA = (const void*)(Pb + (size_t)(rbase + rr) * N_K + kel + (gc << 3));
      uint32_t off = (uint32_t)(buf * 32768 + (((wid << 5) + (i << 3)) << 7));
      off = (uint32_t)__builtin_amdgcn_readfirstlane((int)off);
      gload16(gA, smem + off);
    }
#pragma unroll
    for (int i = 0; i < 4; ++i) {
      const int rr = (wid << 5) + (i << 3) + lrow;
      const int gc = lchk ^ (rr & 7);
      const void* gB = (const void*)(Vt + (size_t)(cbase + rr) * N_K + kel + (gc << 3));
      uint32_t off = (uint32_t)(buf * 32768 + 16384 + (((wid << 5) + (i << 3)) << 7));
      off = (uint32_t)__builtin_amdgcn_readfirstlane((int)off);
      gload16(gB, smem + off);
    }
  };

  auto compute = [&](int buf) {
    const char* bA = smem + buf * 32768;
    const char* bB = bA + 16384;
#pragma unroll
    for (int kh = 0; kh < 2; ++kh) {
      bf16x8 a[4], b[4];
#pragma unroll
      for (int m = 0; m < 4; ++m) {
        int row = (wr << 6) + (m << 4) + (lane & 15);
        uint32_t co = (uint32_t)(((((kh << 2) + (lane >> 4)) << 4)) ^ ((row & 7) << 4));
        a[m] = *(const bf16x8*)(bA + row * 128 + co);
      }
#pragma unroll
      for (int n = 0; n < 4; ++n) {
        int row = (wc << 6) + (n << 4) + (lane & 15);
        uint32_t co = (uint32_t)(((((kh << 2) + (lane >> 4)) << 4)) ^ ((row & 7) << 4));
        b[n] = *(const bf16x8*)(bB + row * 128 + co);
      }
#pragma unroll
      for (int m = 0; m < 4; ++m)
#pragma unroll
        for (int n = 0; n < 4; ++n)
          acc[m][n] = mfma_bf16(a[m], b[n], acc[m][n]);
    }
  };

  stage(0, 0);
  __syncthreads();
  int cur = 0;
  for (int t = 0; t < iters; ++t) {
    if (t + 1 < iters) stage(cur ^ 1, t + 1);
    compute(cur);
    __syncthreads();
    cur ^= 1;
  }

#pragma unroll
  for (int m = 0; m < 4; ++m) {
    int row = rbase + wr * 64 + m * 16 + (lane >> 4) * 4;
#pragma unroll
    for (int n = 0; n < 4; ++n) {
      int col = cbase + wc * 64 + n * 16 + (lane & 15);
#pragma unroll
      for (int j = 0; j < 4; ++j)
        Out[(size_t)(row + j) * DIM + col] = acc[m][n][j];
    }
  }
}

__global__ __launch_bounds__(256) void reduce_kernel(float* __restrict__ O,
                                                     const float* __restrict__ Opart,
                                                     int nsplit) {
  size_t i = ((size_t)blockIdx.x * 256 + threadIdx.x) * 4;
  f32x4 s = *(const f32x4*)(Opart + i);
  for (int z = 1; z < nsplit; ++z)
    s += *(const f32x4*)(Opart + (size_t)z * ((size_t)N_Q * DIM) + i);
  *(f32x4*)(O + i) = s;
}

// ---------------------------------------------------------------------------
// Fallback PV (round-1), used only if ws is too small
// ---------------------------------------------------------------------------
__global__ __launch_bounds__(512, 2) void pv_kernel(const float* __restrict__ P,
                                                    const float* __restrict__ V,
                                                    float* __restrict__ O) {
  __shared__ __align__(16) char sA[16384];
  __shared__ __align__(16) char sB[16384];

  const int tid = threadIdx.x;
  const int rbase = blockIdx.y * 128;
  const int cbase = blockIdx.x * 128;
  const int lane = tid & 63, wid = tid >> 6;
  const int wr = wid >> 2, wc = wid & 3;
  const int lr = lane & 15, lk = (lane >> 4) * 8;

  const int a_row = tid >> 4;
  const int a_col = (tid & 15) * 4;
  const int b_c = tid & 127;
  const int b_oct = tid >> 7;

  f32x4 areg[4];
  float breg[4][4];
#pragma unroll
  for (int p = 0; p < 4; ++p) {
    int r = p * 32 + a_row;
    areg[p] = *(const f32x4*)(P + (size_t)(rbase + r) * N_K + a_col);
  }
#pragma unroll
  for (int g = 0; g < 4; ++g) {
    int kr0 = b_oct * 4 + g * 16;
#pragma unroll
    for (int i = 0; i < 4; ++i)
      breg[g][i] = V[(size_t)(kr0 + i) * DIM + cbase + b_c];
  }

  const f32x4 fzero = {0.f, 0.f, 0.f, 0.f};
  f32x4 acc[4][2];
#pragma unroll
  for (int m = 0; m < 4; ++m)
#pragma unroll
    for (int n = 0; n < 2; ++n) acc[m][n] = fzero;

  for (int kk = 0; kk < N_K / 64; ++kk) {
    __syncthreads();
#pragma unroll
    for (int p = 0; p < 4; ++p) {
      int r = p * 32 + a_row;
      uint32_t bo = (uint32_t)(r * 128) + (uint32_t)((a_col * 2) ^ ((r & 7) << 4));
      u16x4 hv;
#pragma unroll
      for (int i = 0; i < 4; ++i) hv[i] = bf16r(areg[p][i]);
      *(u16x4*)(sA + bo) = hv;
    }
#pragma unroll
    for (int g = 0; g < 4; ++g) {
      int kr0 = b_oct * 4 + g * 16;
      uint32_t bo = (uint32_t)(b_c * 128) + (uint32_t)((kr0 * 2) ^ ((b_c & 7) << 4));
      u16x4 hv;
#pragma unroll
      for (int i = 0; i < 4; ++i) hv[i] = bf16r(breg[g][i]);
      *(u16x4*)(sB + bo) = hv;
    }
    __syncthreads();
    if (kk < N_K / 64 - 1) {
#pragma unroll
      for (int p = 0; p < 4; ++p) {
        int r = p * 32 + a_row;
        areg[p] = *(const f32x4*)(P + (size_t)(rbase + r) * N_K + (kk + 1) * 64 + a_col);
      }
#pragma unroll
      for (int g = 0; g < 4; ++g) {
        int kr0 = b_oct * 4 + g * 16;
#pragma unroll
        for (int i = 0; i < 4; ++i)
          breg[g][i] = V[(size_t)((kk + 1) * 64 + kr0 + i) * DIM + cbase + b_c];
      }
    }
#pragma unroll
    for (int kh = 0; kh < 2; ++kh) {
      bf16x8 af[4], bf[2];
#pragma unroll
      for (int m = 0; m < 4; ++m) {
        int row = wr * 64 + m * 16 + lr;
        uint32_t co = (uint32_t)(((kh * 32 + lk) * 2) ^ ((row & 7) << 4));
        af[m] = *(const bf16x8*)(sA + row * 128 + co);
      }
#pragma unroll
      for (int n = 0; n < 2; ++n) {
        int row = wc * 32 + n * 16 + lr;
        uint32_t co = (uint32_t)(((kh * 32 + lk) * 2) ^ ((row & 7) << 4));
        bf[n] = *(const bf16x8*)(sB + row * 128 + co);
      }
#pragma unroll
      for (int m = 0; m < 4; ++m)
#pragma unroll
        for (int n = 0; n < 2; ++n)
          acc[m][n] = mfma_bf16(af[m], bf[n], acc[m][n]);
    }
  }

#pragma unroll
  for (int m = 0; m < 4; ++m) {
    int row = rbase + wr * 64 + m * 16 + (lane >> 4) * 4;
#pragma unroll
    for (int n = 0; n < 2; ++n) {
      int col = cbase + wc * 32 + n * 16 + lr;
#pragma unroll
      for (int j = 0; j < 4; ++j)
        O[(size_t)(row + j) * DIM + col] = acc[m][n][j];
    }
  }
}

extern "C" void kernel_launch(void* const* d_in, const int* in_sizes, int n_in,
                              void* d_out, int out_size, void* d_ws, size_t ws_size,
                              hipStream_t stream) {
  const float* Q = (const float*)d_in[0];
  const float* K = (const float*)d_in[1];
  const float* V = (const float*)d_in[2];
  float* O = (float*)d_out;                       // [4096, 512]
  float* P = O + (size_t)N_Q * DIM;               // [4096, 4096] probs

  const size_t PB_BYTES = (size_t)N_Q * N_K * 2;          // 32 MB
  const size_t VT_BYTES = (size_t)DIM * N_K * 2;          // 4 MB
  const size_t SCL_BYTES = 65536;                          // 64 KB (2x16KB used)
  const size_t OP_BYTES = (size_t)N_Q * DIM * 4;          // 8 MB per split

  int nsplit = 0;
  if (ws_size >= PB_BYTES + VT_BYTES + SCL_BYTES + 4 * OP_BYTES) nsplit = 4;
  else if (ws_size >= PB_BYTES + VT_BYTES + SCL_BYTES + 2 * OP_BYTES) nsplit = 2;
  else if (ws_size >= PB_BYTES + VT_BYTES + SCL_BYTES) nsplit = 1;

  if (nsplit > 0) {
    char* wsb = (char*)d_ws;
    // Xq8/Xk8 (4 MB each) alias the first 8 MB of Pb — dead before softmax.
    signed char* Xq8 = (signed char*)wsb;
    signed char* Xk8 = Xq8 + (size_t)N_Q * 1024;
    unsigned short* Pb = (unsigned short*)wsb;
    unsigned short* Vt = (unsigned short*)(wsb + PB_BYTES);
    float* sclA = (float*)(wsb + PB_BYTES + VT_BYTES);
    float* sclB = sclA + N_Q;
    float* Opart = (float*)(wsb + PB_BYTES + VT_BYTES + SCL_BYTES);

    quant_kernel<<<dim3(N_Q / 4, 2), 256, 0, stream>>>(Q, K, Xq8, Xk8, sclA, sclB);
    vt_kernel<<<dim3(DIM / 64, N_K / 64), 256, 0, stream>>>(V, Vt);
    qk3_kernel<<<1024, 256, 0, stream>>>(Xq8, Xk8, sclA, sclB, P);
    softmax_kernel<<<N_Q, 256, 0, stream>>>(P, Pb);
    if (nsplit == 1) {
      pv3_kernel<<<dim3(DIM / 128, N_Q / 128, 1), 256, 0, stream>>>(Pb, Vt, O, N_K);
    } else {
      pv3_kernel<<<dim3(DIM / 128, N_Q / 128, nsplit), 256, 0, stream>>>(Pb, Vt, Opart, N_K / nsplit);
      reduce_kernel<<<(N_Q * DIM) / (256 * 4), 256, 0, stream>>>(O, Opart, nsplit);
    }
  } else {
    qk_kernel<<<dim3(N_K / 128, N_Q / 128), 256, 0, stream>>>(Q, K, P);
    softmax_kernel<<<N_Q, 256, 0, stream>>>(P, nullptr);
    pv_kernel<<<dim3(DIM / 128, N_Q / 128), 512, 0, stream>>>(P, V, O);
  }
}